// Round 17
// baseline (23.888 us; speedup 1.0000x reference)
//
#include <hip/hip_runtime.h>
#include <math.h>

// Tensor-train log-likelihood, B=256, T=1024, d=4, D=32.
// Round 17: split the block-invariant pair table out of the fused kernel.
//  - tt_pair_kernel <<<1,1024>>>: 16 waves build the 16 pair products
//    P = M_a @ M_b (r16 phase-1 code verbatim), rowsum-normalized exact
//    pow-2, emitted as sigma-fragments to GLOBAL g_PT (32 KB, L2-resident)
//    + g_kP exponents.
//  - tt_main_kernel <<<256,1024>>>: chain reads pairs via the r14-validated
//    asm global-load ledger (2 loads/step, 4 banks, vmcnt(6), drain 0) --
//    zero LDS traffic in the chain (was ~1 MB/block on the LDS pipe, the
//    r16 bottleneck). Indices: one int4 per 4 steps (r14). No in-chain
//    rescale (rowsum norm => ||S||_1 <= 2^32 over 32 steps, r16-validated).
//    Tree (16->8->4->2->1 ping-pong) + epilogue verbatim r15/r16.

#define TT_B 256
#define TT_T 1024

typedef __attribute__((ext_vector_type(8))) short bf16x8;
typedef __attribute__((ext_vector_type(4))) float f32x4;

// Pair fragment table: [m][H][lane] = uint4 (sigma form), 2KB per pair.
__device__ uint4 g_PT[16 * 2 * 64];
__device__ int   g_kP[16];

__device__ __forceinline__ unsigned pkbf16(float lo, float hi)
{
    unsigned r;
    asm volatile("v_cvt_pk_bf16_f32 %0, %1, %2" : "=v"(r) : "v"(lo), "v"(hi));
    return r;
}
__device__ __forceinline__ bf16x8 as_bf16x8(int4 v)
{ union { int4 i; bf16x8 h; } u; u.i = v; return u.h; }
__device__ __forceinline__ bf16x8 as_bf16x8u(uint4 v)
{ union { uint4 i; bf16x8 h; } u; u.i = v; return u.h; }

#define MAXD4(D) fmaxf(fmaxf(fabsf(D[0]), fabsf(D[1])), fmaxf(fabsf(D[2]), fabsf(D[3])))

// tree node (r13-validated, verbatim): node(Ma, Mb) = Mb @ Ma (physical),
// f32 LDS [32][36] both sides, output rescaled by exact pow-2, exp returned.
__device__ __forceinline__ int tree_node_lds(const float* __restrict__ Ma,
                                             const float* __restrict__ Mb,
                                             float* __restrict__ Mdst, int lane)
{
    const int p = lane & 15, q = lane >> 4;
    const float4 a00 = *(const float4*)(Mb + p * 36 + 8 * q);
    const float4 a01 = *(const float4*)(Mb + p * 36 + 8 * q + 4);
    const float4 a10 = *(const float4*)(Mb + (16 + p) * 36 + 8 * q);
    const float4 a11 = *(const float4*)(Mb + (16 + p) * 36 + 8 * q + 4);
    int4 aw0, aw1;
    aw0.x = (int)pkbf16(a00.x, a00.y); aw0.y = (int)pkbf16(a00.z, a00.w);
    aw0.z = (int)pkbf16(a01.x, a01.y); aw0.w = (int)pkbf16(a01.z, a01.w);
    aw1.x = (int)pkbf16(a10.x, a10.y); aw1.y = (int)pkbf16(a10.z, a10.w);
    aw1.z = (int)pkbf16(a11.x, a11.y); aw1.w = (int)pkbf16(a11.z, a11.w);
    int4 bw0, bw1;
    bw0.x = (int)pkbf16(Ma[(8*q+0)*36 + p], Ma[(8*q+1)*36 + p]);
    bw0.y = (int)pkbf16(Ma[(8*q+2)*36 + p], Ma[(8*q+3)*36 + p]);
    bw0.z = (int)pkbf16(Ma[(8*q+4)*36 + p], Ma[(8*q+5)*36 + p]);
    bw0.w = (int)pkbf16(Ma[(8*q+6)*36 + p], Ma[(8*q+7)*36 + p]);
    bw1.x = (int)pkbf16(Ma[(8*q+0)*36 + 16 + p], Ma[(8*q+1)*36 + 16 + p]);
    bw1.y = (int)pkbf16(Ma[(8*q+2)*36 + 16 + p], Ma[(8*q+3)*36 + 16 + p]);
    bw1.z = (int)pkbf16(Ma[(8*q+4)*36 + 16 + p], Ma[(8*q+5)*36 + 16 + p]);
    bw1.w = (int)pkbf16(Ma[(8*q+6)*36 + 16 + p], Ma[(8*q+7)*36 + 16 + p]);

    const bf16x8 af0 = as_bf16x8(aw0), af1 = as_bf16x8(aw1);
    const bf16x8 bf0 = as_bf16x8(bw0), bf1 = as_bf16x8(bw1);
    const f32x4 zero = {0.f, 0.f, 0.f, 0.f};
    f32x4 d00 = __builtin_amdgcn_mfma_f32_16x16x32_bf16(af0, bf0, zero, 0, 0, 0);
    f32x4 d01 = __builtin_amdgcn_mfma_f32_16x16x32_bf16(af0, bf1, zero, 0, 0, 0);
    f32x4 d10 = __builtin_amdgcn_mfma_f32_16x16x32_bf16(af1, bf0, zero, 0, 0, 0);
    f32x4 d11 = __builtin_amdgcn_mfma_f32_16x16x32_bf16(af1, bf1, zero, 0, 0, 0);

    float zm = fmaxf(fmaxf(MAXD4(d00), MAXD4(d01)), fmaxf(MAXD4(d10), MAXD4(d11)));
    zm = fmaxf(zm, __shfl_xor(zm,  1));
    zm = fmaxf(zm, __shfl_xor(zm,  2));
    zm = fmaxf(zm, __shfl_xor(zm,  4));
    zm = fmaxf(zm, __shfl_xor(zm,  8));
    zm = fmaxf(zm, __shfl_xor(zm, 16));
    zm = fmaxf(zm, __shfl_xor(zm, 32));
    const int eb = __float_as_int(zm) & 0x7f800000;
    const float s = __int_as_float(0x7F000000 - eb);
#pragma unroll
    for (int t = 0; t < 4; ++t) {
        Mdst[(4*q + t) * 36 + p]           = d00[t] * s;
        Mdst[(4*q + t) * 36 + 16 + p]      = d01[t] * s;
        Mdst[(16 + 4*q + t) * 36 + p]      = d10[t] * s;
        Mdst[(16 + 4*q + t) * 36 + 16 + p] = d11[t] * s;
    }
    return (eb >> 23) - 127;
}

// ---- pair-table builder: 1 block, wave w builds P_w = M_{w>>2} @ M_{w&3} --

__global__ __launch_bounds__(1024) void tt_pair_kernel(const float* __restrict__ core)
{
    __shared__ __align__(16) float Cs[4 * 1152];

    const int tid  = threadIdx.x;
    const int wid  = tid >> 6;
    const int lane = tid & 63;
    const int p = lane & 15, q = lane >> 4;

    if (wid < 4) {                    // load 4 cores into [32][36] slots
        const int r = lane >> 1, hh = (lane & 1) * 16;
        const float4* s4 = (const float4*)(core + wid * 1024 + r * 32 + hh);
        float4 v0 = s4[0], v1 = s4[1], v2 = s4[2], v3 = s4[3];
        float4* d4 = (float4*)(Cs + wid * 1152 + r * 36 + hh);
        d4[0] = v0; d4[1] = v1; d4[2] = v2; d4[3] = v3;
    }
    __syncthreads();

    const f32x4 zero = {0.f, 0.f, 0.f, 0.f};
    // r16 phase-1 verbatim: P = M_{wid>>2} @ M_{wid&3}
    const float* Pa = Cs + (wid & 3) * 1152;    // B-frag source (scalar cols)
    const float* Pb = Cs + (wid >> 2) * 1152;   // A-frag source (float4 rows)
    const float4 a00 = *(const float4*)(Pb + p * 36 + 8 * q);
    const float4 a01 = *(const float4*)(Pb + p * 36 + 8 * q + 4);
    const float4 a10 = *(const float4*)(Pb + (16 + p) * 36 + 8 * q);
    const float4 a11 = *(const float4*)(Pb + (16 + p) * 36 + 8 * q + 4);
    int4 aw0, aw1;
    aw0.x = (int)pkbf16(a00.x, a00.y); aw0.y = (int)pkbf16(a00.z, a00.w);
    aw0.z = (int)pkbf16(a01.x, a01.y); aw0.w = (int)pkbf16(a01.z, a01.w);
    aw1.x = (int)pkbf16(a10.x, a10.y); aw1.y = (int)pkbf16(a10.z, a10.w);
    aw1.z = (int)pkbf16(a11.x, a11.y); aw1.w = (int)pkbf16(a11.z, a11.w);
    int4 bw0, bw1;
    bw0.x = (int)pkbf16(Pa[(8*q+0)*36 + p], Pa[(8*q+1)*36 + p]);
    bw0.y = (int)pkbf16(Pa[(8*q+2)*36 + p], Pa[(8*q+3)*36 + p]);
    bw0.z = (int)pkbf16(Pa[(8*q+4)*36 + p], Pa[(8*q+5)*36 + p]);
    bw0.w = (int)pkbf16(Pa[(8*q+6)*36 + p], Pa[(8*q+7)*36 + p]);
    bw1.x = (int)pkbf16(Pa[(8*q+0)*36 + 16 + p], Pa[(8*q+1)*36 + 16 + p]);
    bw1.y = (int)pkbf16(Pa[(8*q+2)*36 + 16 + p], Pa[(8*q+3)*36 + 16 + p]);
    bw1.z = (int)pkbf16(Pa[(8*q+4)*36 + 16 + p], Pa[(8*q+5)*36 + 16 + p]);
    bw1.w = (int)pkbf16(Pa[(8*q+6)*36 + 16 + p], Pa[(8*q+7)*36 + 16 + p]);
    const bf16x8 af0 = as_bf16x8(aw0), af1 = as_bf16x8(aw1);
    const bf16x8 bf0 = as_bf16x8(bw0), bf1 = as_bf16x8(bw1);
    f32x4 d00 = __builtin_amdgcn_mfma_f32_16x16x32_bf16(af0, bf0, zero, 0, 0, 0);
    f32x4 d01 = __builtin_amdgcn_mfma_f32_16x16x32_bf16(af0, bf1, zero, 0, 0, 0);
    f32x4 d10 = __builtin_amdgcn_mfma_f32_16x16x32_bf16(af1, bf0, zero, 0, 0, 0);
    f32x4 d11 = __builtin_amdgcn_mfma_f32_16x16x32_bf16(af1, bf1, zero, 0, 0, 0);

    // rowsum-normalize (exact pow-2) -- r16 verbatim
    float rs[4], ru[4];
#pragma unroll
    for (int t = 0; t < 4; ++t) {
        rs[t] = fabsf(d00[t]) + fabsf(d01[t]);
        ru[t] = fabsf(d10[t]) + fabsf(d11[t]);
    }
#pragma unroll
    for (int sh = 1; sh <= 8; sh <<= 1) {
#pragma unroll
        for (int t = 0; t < 4; ++t) {
            rs[t] += __shfl_xor(rs[t], sh);
            ru[t] += __shfl_xor(ru[t], sh);
        }
    }
    float mx = fmaxf(fmaxf(fmaxf(rs[0], rs[1]), fmaxf(rs[2], rs[3])),
                     fmaxf(fmaxf(ru[0], ru[1]), fmaxf(ru[2], ru[3])));
    mx = fmaxf(mx, __shfl_xor(mx, 16));
    mx = fmaxf(mx, __shfl_xor(mx, 32));
    const int eb = __float_as_int(mx) & 0x7f800000;
    const float s = __int_as_float(0x7F000000 - eb);
    if (lane == 0) g_kP[wid] = (eb >> 23) - 127;

    uint4 H0, H1;
    H0.x = pkbf16(d00[0]*s, d00[1]*s);  H0.y = pkbf16(d00[2]*s, d00[3]*s);
    H0.z = pkbf16(d10[0]*s, d10[1]*s);  H0.w = pkbf16(d10[2]*s, d10[3]*s);
    H1.x = pkbf16(d01[0]*s, d01[1]*s);  H1.y = pkbf16(d01[2]*s, d01[3]*s);
    H1.z = pkbf16(d11[0]*s, d11[1]*s);  H1.w = pkbf16(d11[2]*s, d11[3]*s);
    g_PT[wid * 128 + lane]      = H0;
    g_PT[wid * 128 + 64 + lane] = H1;
}

// ---- main kernel -----------------------------------------------------------

// r14-validated asm prefetch: SGPR base + per-lane VGPR offset (2KB stride).
#define LOAD2(UB0, UB1, MIDX) do {                                            \
    const int voff_ = (((MIDX) << 11) | (lane << 4));                         \
    asm volatile("global_load_dwordx4 %0, %1, %2"             : "=v"(UB0) : "v"(voff_), "s"(qtb)); \
    asm volatile("global_load_dwordx4 %0, %1, %2 offset:1024" : "=v"(UB1) : "v"(voff_), "s"(qtb)); \
} while (0)

// One sigma-chain step (r15 no-rescale MSTEP verbatim): wait own bank
// (6 = 3 banks in flight), S' = P^T @ S via 4 MFMA, reload same bank for
// t+4, pack D -> S (8 pkbf16) or (DO_LAST) write f32 D to LDS (m89 layout).
#define MSTEP(UB0, UB1, MIDX, DO_LAST) do {                                   \
    const bf16x8 sb0 = as_bf16x8u(make_uint4(S0w, S1w, S2w, S3w));            \
    const bf16x8 sb1 = as_bf16x8u(make_uint4(S4w, S5w, S6w, S7w));            \
    asm volatile("s_waitcnt vmcnt(6)" ::: "memory");                          \
    __builtin_amdgcn_sched_barrier(0);                                        \
    const bf16x8 af0 = as_bf16x8(UB0);                                        \
    const bf16x8 af1 = as_bf16x8(UB1);                                        \
    f32x4 d00 = __builtin_amdgcn_mfma_f32_16x16x32_bf16(af0, sb0, zero, 0, 0, 0); \
    f32x4 d01 = __builtin_amdgcn_mfma_f32_16x16x32_bf16(af0, sb1, zero, 0, 0, 0); \
    f32x4 d10 = __builtin_amdgcn_mfma_f32_16x16x32_bf16(af1, sb0, zero, 0, 0, 0); \
    f32x4 d11 = __builtin_amdgcn_mfma_f32_16x16x32_bf16(af1, sb1, zero, 0, 0, 0); \
    LOAD2(UB0, UB1, (MIDX));                                                  \
    if (DO_LAST) {                                                            \
        _Pragma("unroll") for (int u_ = 0; u_ < 4; ++u_) {                    \
            Mseg[(4*g + u_) * 36 + jj]           = d00[u_];                   \
            Mseg[(4*g + u_) * 36 + 16 + jj]      = d01[u_];                   \
            Mseg[(16 + 4*g + u_) * 36 + jj]      = d10[u_];                   \
            Mseg[(16 + 4*g + u_) * 36 + 16 + jj] = d11[u_];                   \
        }                                                                     \
    } else {                                                                  \
        S0w = pkbf16(d00[0], d00[1]);  S1w = pkbf16(d00[2], d00[3]);          \
        S2w = pkbf16(d10[0], d10[1]);  S3w = pkbf16(d10[2], d10[3]);          \
        S4w = pkbf16(d01[0], d01[1]);  S5w = pkbf16(d01[2], d01[3]);          \
        S6w = pkbf16(d11[0], d11[1]);  S7w = pkbf16(d11[2], d11[3]);          \
    }                                                                         \
} while (0)

__global__ __launch_bounds__(1024, 1) void tt_main_kernel(const int* __restrict__ X,
                                                          const float* __restrict__ Lb,
                                                          const float* __restrict__ Rb,
                                                          float* __restrict__ out)
{
    __shared__ __align__(16) int   pidx[544];
    __shared__ __align__(16) float Ms[24 * 1152];  // 16 seg + 8 ping-pong
    __shared__ int   kPl[16];
    __shared__ int   EcA[16];
    __shared__ int   kpart[16];

    const int b    = blockIdx.x;
    const int tid  = threadIdx.x;
    const int wid  = tid >> 6;        // 0..15
    const int lane = tid & 63;
    const int g = lane >> 4, jj = lane & 15;

    // ---- phase 0: parse X -> pair indices; load exponent table ------------
    if (tid < 512) {
        const int2 xv = ((const int2*)(X + (size_t)b * TT_T))[tid];
        pidx[tid] = xv.x * 4 + xv.y;
    } else if (tid < 544) {
        pidx[tid] = 0;                // pad for chain lookahead
    }
    if (tid < 16) { kPl[tid] = g_kP[tid]; EcA[tid] = 0; }
    __syncthreads();

    // ---- phase 1: per-sequence exponent sum over 512 pair-applications ----
    int ksum = 0;
    if (tid < 512) ksum = kPl[pidx[tid]];
    ksum += __shfl_xor(ksum,  1);
    ksum += __shfl_xor(ksum,  2);
    ksum += __shfl_xor(ksum,  4);
    ksum += __shfl_xor(ksum,  8);
    ksum += __shfl_xor(ksum, 16);
    ksum += __shfl_xor(ksum, 32);
    if (lane == 0) kpart[wid] = ksum;    // waves 8..15 contribute 0

    const uint4* qtb = g_PT;             // compile-time global -> SGPR base
    const f32x4 zero = {0.f, 0.f, 0.f, 0.f};

    // ---- phase 2: chain. wave w: pairs [32w, 32w+32), S = (prod P)^T ------
    const int base4 = 8 * wid;
    const int4* idxs4 = (const int4*)pidx;
    float* Mseg = Ms + wid * 1152;

    // identity S (sigma form)
    unsigned S0w, S1w, S2w, S3w, S4w, S5w, S6w, S7w;
    {
        const unsigned e0 = ((4*g+0 == jj) ? 0x3F80u : 0u) | ((4*g+1 == jj) ? 0x3F800000u : 0u);
        const unsigned e1 = ((4*g+2 == jj) ? 0x3F80u : 0u) | ((4*g+3 == jj) ? 0x3F800000u : 0u);
        S0w = e0; S1w = e1; S2w = 0u; S3w = 0u;
        S4w = 0u; S5w = 0u; S6w = e0; S7w = e1;
    }

    int4 Ba0, Ba1, Bb0, Bb1, Bc0, Bc1, Bd0, Bd1;
    {
        const int4 m0 = idxs4[base4];        // steps 0..3
        LOAD2(Ba0, Ba1, m0.x);
        LOAD2(Bb0, Bb1, m0.y);
        LOAD2(Bc0, Bc1, m0.z);
        LOAD2(Bd0, Bd1, m0.w);
    }
    int4 mqc = idxs4[base4 + 1];             // reload indices for steps 4..7

#pragma unroll 1
    for (int J = 0; J < 8; ++J) {
        const int4 mq_nx = idxs4[base4 + J + 2];   // J=7 reads zero padding
        const bool lt = (J == 7);                  // step 31 writes LDS
        MSTEP(Ba0, Ba1, mqc.x, 0);
        MSTEP(Bb0, Bb1, mqc.y, 0);
        MSTEP(Bc0, Bc1, mqc.z, 0);
        MSTEP(Bd0, Bd1, mqc.w, lt);
        mqc = mq_nx;
    }

    // drain tail prefetches before any reuse (r3 lesson)
    asm volatile("s_waitcnt vmcnt(0)" ::: "memory");
    __syncthreads();

    // ---- phase 3: tree 16 -> 8 -> 4 -> 2 -> 1, ping-pong slots (r15/r16) --
    if (wid < 8) {
        const int ec = tree_node_lds(Ms + (2*wid) * 1152, Ms + (2*wid + 1) * 1152,
                                     Ms + (16 + wid) * 1152, lane);
        if (lane == 0) EcA[wid] = ec;
    }
    __syncthreads();
    if (wid < 4) {
        const int ec = tree_node_lds(Ms + (16 + 2*wid) * 1152, Ms + (16 + 2*wid + 1) * 1152,
                                     Ms + wid * 1152, lane);
        if (lane == 0) EcA[8 + wid] = ec;
    }
    __syncthreads();
    if (wid < 2) {
        const int ec = tree_node_lds(Ms + (2*wid) * 1152, Ms + (2*wid + 1) * 1152,
                                     Ms + (16 + wid) * 1152, lane);
        if (lane == 0) EcA[12 + wid] = ec;
    }
    __syncthreads();
    int ecL4 = 0;
    if (wid == 0) {
        ecL4 = tree_node_lds(Ms + 16 * 1152, Ms + 17 * 1152, Ms, lane);
    }

    // ---- phase 4: epilogue: out = L^T P R; S_tot = P^T in slot 0 ----------
    if (wid == 0 && lane < 32) {
        const float* Mt = Ms;
        float v = 0.f;
#pragma unroll 8
        for (int c2 = 0; c2 < 32; ++c2) v = fmaf(Rb[c2], Mt[c2 * 36 + lane], v);
        float pp = v * Lb[lane];
        pp += __shfl_xor(pp,  1);
        pp += __shfl_xor(pp,  2);
        pp += __shfl_xor(pp,  4);
        pp += __shfl_xor(pp,  8);
        pp += __shfl_xor(pp, 16);
        if (lane == 0) {
            int S = ecL4;
#pragma unroll
            for (int w = 0; w < 16; ++w) S += EcA[w] + kpart[w];
            out[b] = 2.0f * ((float)S * 0.6931471805599453f + logf(fabsf(pp)));
        }
    }
}

extern "C" void kernel_launch(void* const* d_in, const int* in_sizes, int n_in,
                              void* d_out, int out_size, void* d_ws, size_t ws_size,
                              hipStream_t stream)
{
    const int*   X    = (const int*)d_in[0];
    const float* core = (const float*)d_in[1];
    const float* Lb   = (const float*)d_in[2];
    const float* Rb   = (const float*)d_in[3];
    float* out = (float*)d_out;

    tt_pair_kernel<<<dim3(1),   dim3(1024), 0, stream>>>(core);
    tt_main_kernel<<<dim3(256), dim3(1024), 0, stream>>>(X, Lb, Rb, out);
}

// Round 18
// 21.778 us; speedup vs baseline: 1.0969x; 1.0969x over previous
//
#include <hip/hip_runtime.h>
#include <math.h>

// Tensor-train log-likelihood, B=256, T=1024, d=4, D=32.
// Round 18 = round 16 (best, 21.02us, PASS absmax 0) + depth-2 LDS software
// pipeline in the chain: pair fragments fetched 2 steps ahead (triple-
// buffered F regs), indices 3 steps ahead -- splits the 240cy serial
// pidx->Ptab dependent chain into two overlapped 120cy stages. r17's
// global-table split is REVERTED (regressed +2.9us: chain was not
// LDS-throughput-bound; the split only added launch + serial kernel).
// All math verbatim r16: per-block LDS pair table (16 pairs, rowsum-
// normalized exact pow-2), 16 waves x 32 pair-steps, tree 16->8->4->2->1,
// epilogue fold. No global tables, no asm loads, single kernel.

#define TT_B 256
#define TT_T 1024

typedef __attribute__((ext_vector_type(8))) short bf16x8;
typedef __attribute__((ext_vector_type(4))) float f32x4;

__device__ __forceinline__ unsigned pkbf16(float lo, float hi)
{
    unsigned r;
    asm volatile("v_cvt_pk_bf16_f32 %0, %1, %2" : "=v"(r) : "v"(lo), "v"(hi));
    return r;
}
__device__ __forceinline__ bf16x8 as_bf16x8(int4 v)
{ union { int4 i; bf16x8 h; } u; u.i = v; return u.h; }
__device__ __forceinline__ bf16x8 as_bf16x8u(uint4 v)
{ union { uint4 i; bf16x8 h; } u; u.i = v; return u.h; }

#define MAXD4(D) fmaxf(fmaxf(fabsf(D[0]), fabsf(D[1])), fmaxf(fabsf(D[2]), fabsf(D[3])))

// tree node (r13-validated, verbatim): node(Ma, Mb) = Mb @ Ma (physical),
// f32 LDS [32][36] both sides, output rescaled by exact pow-2, exp returned.
__device__ __forceinline__ int tree_node_lds(const float* __restrict__ Ma,
                                             const float* __restrict__ Mb,
                                             float* __restrict__ Mdst, int lane)
{
    const int p = lane & 15, q = lane >> 4;
    const float4 a00 = *(const float4*)(Mb + p * 36 + 8 * q);
    const float4 a01 = *(const float4*)(Mb + p * 36 + 8 * q + 4);
    const float4 a10 = *(const float4*)(Mb + (16 + p) * 36 + 8 * q);
    const float4 a11 = *(const float4*)(Mb + (16 + p) * 36 + 8 * q + 4);
    int4 aw0, aw1;
    aw0.x = (int)pkbf16(a00.x, a00.y); aw0.y = (int)pkbf16(a00.z, a00.w);
    aw0.z = (int)pkbf16(a01.x, a01.y); aw0.w = (int)pkbf16(a01.z, a01.w);
    aw1.x = (int)pkbf16(a10.x, a10.y); aw1.y = (int)pkbf16(a10.z, a10.w);
    aw1.z = (int)pkbf16(a11.x, a11.y); aw1.w = (int)pkbf16(a11.z, a11.w);
    int4 bw0, bw1;
    bw0.x = (int)pkbf16(Ma[(8*q+0)*36 + p], Ma[(8*q+1)*36 + p]);
    bw0.y = (int)pkbf16(Ma[(8*q+2)*36 + p], Ma[(8*q+3)*36 + p]);
    bw0.z = (int)pkbf16(Ma[(8*q+4)*36 + p], Ma[(8*q+5)*36 + p]);
    bw0.w = (int)pkbf16(Ma[(8*q+6)*36 + p], Ma[(8*q+7)*36 + p]);
    bw1.x = (int)pkbf16(Ma[(8*q+0)*36 + 16 + p], Ma[(8*q+1)*36 + 16 + p]);
    bw1.y = (int)pkbf16(Ma[(8*q+2)*36 + 16 + p], Ma[(8*q+3)*36 + 16 + p]);
    bw1.z = (int)pkbf16(Ma[(8*q+4)*36 + 16 + p], Ma[(8*q+5)*36 + 16 + p]);
    bw1.w = (int)pkbf16(Ma[(8*q+6)*36 + 16 + p], Ma[(8*q+7)*36 + 16 + p]);

    const bf16x8 af0 = as_bf16x8(aw0), af1 = as_bf16x8(aw1);
    const bf16x8 bf0 = as_bf16x8(bw0), bf1 = as_bf16x8(bw1);
    const f32x4 zero = {0.f, 0.f, 0.f, 0.f};
    f32x4 d00 = __builtin_amdgcn_mfma_f32_16x16x32_bf16(af0, bf0, zero, 0, 0, 0);
    f32x4 d01 = __builtin_amdgcn_mfma_f32_16x16x32_bf16(af0, bf1, zero, 0, 0, 0);
    f32x4 d10 = __builtin_amdgcn_mfma_f32_16x16x32_bf16(af1, bf0, zero, 0, 0, 0);
    f32x4 d11 = __builtin_amdgcn_mfma_f32_16x16x32_bf16(af1, bf1, zero, 0, 0, 0);

    float zm = fmaxf(fmaxf(MAXD4(d00), MAXD4(d01)), fmaxf(MAXD4(d10), MAXD4(d11)));
    zm = fmaxf(zm, __shfl_xor(zm,  1));
    zm = fmaxf(zm, __shfl_xor(zm,  2));
    zm = fmaxf(zm, __shfl_xor(zm,  4));
    zm = fmaxf(zm, __shfl_xor(zm,  8));
    zm = fmaxf(zm, __shfl_xor(zm, 16));
    zm = fmaxf(zm, __shfl_xor(zm, 32));
    const int eb = __float_as_int(zm) & 0x7f800000;
    const float s = __int_as_float(0x7F000000 - eb);
#pragma unroll
    for (int t = 0; t < 4; ++t) {
        Mdst[(4*q + t) * 36 + p]           = d00[t] * s;
        Mdst[(4*q + t) * 36 + 16 + p]      = d01[t] * s;
        Mdst[(16 + 4*q + t) * 36 + p]      = d10[t] * s;
        Mdst[(16 + 4*q + t) * 36 + 16 + p] = d11[t] * s;
    }
    return (eb >> 23) - 127;
}

__global__ __launch_bounds__(1024, 1) void tt_fused_kernel(const int* __restrict__ X,
                                                           const float* __restrict__ core,
                                                           const float* __restrict__ Lb,
                                                           const float* __restrict__ Rb,
                                                           float* __restrict__ out)
{
    __shared__ __align__(16) float Ms[24 * 1152];   // tree slots; 16..19 alias core
    __shared__ __align__(16) uint4 Ptab[2048];      // 16 pairs x 2 halves x 64 lanes
    __shared__ int pidx[544];
    __shared__ int kP[16];
    __shared__ int EcA[16];
    __shared__ int kpart[16];

    const int b    = blockIdx.x;
    const int tid  = threadIdx.x;
    const int wid  = tid >> 6;        // 0..15
    const int lane = tid & 63;
    const int p = lane & 15, q = lane >> 4;
    const int g = q, jj = p;

    // ---- phase 0: parse X -> pair indices; load core -> slots 16..19 ------
    if (tid < 512) {
        const int2 xv = ((const int2*)(X + (size_t)b * TT_T))[tid];
        pidx[tid] = xv.x * 4 + xv.y;
    } else if (tid < 544) {
        pidx[tid] = 0;                // pad for chain lookahead (depth 3)
    }
    if (tid < 16) EcA[tid] = 0;
    if (wid >= 8 && wid < 12) {
        const int mi = wid - 8;
        const int r = lane >> 1, hh = (lane & 1) * 16;
        const float4* s4 = (const float4*)(core + mi * 1024 + r * 32 + hh);
        float4 v0 = s4[0], v1 = s4[1], v2 = s4[2], v3 = s4[3];
        float4* d4 = (float4*)(Ms + (16 + mi) * 1152 + r * 36 + hh);
        d4[0] = v0; d4[1] = v1; d4[2] = v2; d4[3] = v3;
    }
    __syncthreads();

    const f32x4 zero = {0.f, 0.f, 0.f, 0.f};

    // ---- phase 1: pair table. wave w: P = M_{w>>2} @ M_{w&3} ----------------
    {
        const float* Pa = Ms + (16 + (wid & 3)) * 1152;   // B-frag source (scalar cols)
        const float* Pb = Ms + (16 + (wid >> 2)) * 1152;  // A-frag source (float4 rows)
        const float4 a00 = *(const float4*)(Pb + p * 36 + 8 * q);
        const float4 a01 = *(const float4*)(Pb + p * 36 + 8 * q + 4);
        const float4 a10 = *(const float4*)(Pb + (16 + p) * 36 + 8 * q);
        const float4 a11 = *(const float4*)(Pb + (16 + p) * 36 + 8 * q + 4);
        int4 aw0, aw1;
        aw0.x = (int)pkbf16(a00.x, a00.y); aw0.y = (int)pkbf16(a00.z, a00.w);
        aw0.z = (int)pkbf16(a01.x, a01.y); aw0.w = (int)pkbf16(a01.z, a01.w);
        aw1.x = (int)pkbf16(a10.x, a10.y); aw1.y = (int)pkbf16(a10.z, a10.w);
        aw1.z = (int)pkbf16(a11.x, a11.y); aw1.w = (int)pkbf16(a11.z, a11.w);
        int4 bw0, bw1;
        bw0.x = (int)pkbf16(Pa[(8*q+0)*36 + p], Pa[(8*q+1)*36 + p]);
        bw0.y = (int)pkbf16(Pa[(8*q+2)*36 + p], Pa[(8*q+3)*36 + p]);
        bw0.z = (int)pkbf16(Pa[(8*q+4)*36 + p], Pa[(8*q+5)*36 + p]);
        bw0.w = (int)pkbf16(Pa[(8*q+6)*36 + p], Pa[(8*q+7)*36 + p]);
        bw1.x = (int)pkbf16(Pa[(8*q+0)*36 + 16 + p], Pa[(8*q+1)*36 + 16 + p]);
        bw1.y = (int)pkbf16(Pa[(8*q+2)*36 + 16 + p], Pa[(8*q+3)*36 + 16 + p]);
        bw1.z = (int)pkbf16(Pa[(8*q+4)*36 + 16 + p], Pa[(8*q+5)*36 + 16 + p]);
        bw1.w = (int)pkbf16(Pa[(8*q+6)*36 + 16 + p], Pa[(8*q+7)*36 + 16 + p]);
        const bf16x8 af0 = as_bf16x8(aw0), af1 = as_bf16x8(aw1);
        const bf16x8 bf0 = as_bf16x8(bw0), bf1 = as_bf16x8(bw1);
        f32x4 d00 = __builtin_amdgcn_mfma_f32_16x16x32_bf16(af0, bf0, zero, 0, 0, 0);
        f32x4 d01 = __builtin_amdgcn_mfma_f32_16x16x32_bf16(af0, bf1, zero, 0, 0, 0);
        f32x4 d10 = __builtin_amdgcn_mfma_f32_16x16x32_bf16(af1, bf0, zero, 0, 0, 0);
        f32x4 d11 = __builtin_amdgcn_mfma_f32_16x16x32_bf16(af1, bf1, zero, 0, 0, 0);

        // rowsum-normalize (exact pow-2)
        float rs[4], ru[4];
#pragma unroll
        for (int t = 0; t < 4; ++t) {
            rs[t] = fabsf(d00[t]) + fabsf(d01[t]);
            ru[t] = fabsf(d10[t]) + fabsf(d11[t]);
        }
#pragma unroll
        for (int sh = 1; sh <= 8; sh <<= 1) {
#pragma unroll
            for (int t = 0; t < 4; ++t) {
                rs[t] += __shfl_xor(rs[t], sh);
                ru[t] += __shfl_xor(ru[t], sh);
            }
        }
        float mx = fmaxf(fmaxf(fmaxf(rs[0], rs[1]), fmaxf(rs[2], rs[3])),
                         fmaxf(fmaxf(ru[0], ru[1]), fmaxf(ru[2], ru[3])));
        mx = fmaxf(mx, __shfl_xor(mx, 16));
        mx = fmaxf(mx, __shfl_xor(mx, 32));
        const int eb = __float_as_int(mx) & 0x7f800000;
        const float s = __int_as_float(0x7F000000 - eb);
        if (lane == 0) kP[wid] = (eb >> 23) - 127;

        uint4 H0, H1;
        H0.x = pkbf16(d00[0]*s, d00[1]*s);  H0.y = pkbf16(d00[2]*s, d00[3]*s);
        H0.z = pkbf16(d10[0]*s, d10[1]*s);  H0.w = pkbf16(d10[2]*s, d10[3]*s);
        H1.x = pkbf16(d01[0]*s, d01[1]*s);  H1.y = pkbf16(d01[2]*s, d01[3]*s);
        H1.z = pkbf16(d11[0]*s, d11[1]*s);  H1.w = pkbf16(d11[2]*s, d11[3]*s);
        Ptab[wid * 128 + lane]      = H0;
        Ptab[wid * 128 + 64 + lane] = H1;
    }
    __syncthreads();

    // ---- phase 2: per-sequence exponent sum over 512 pair-applications ----
    int ksum = 0;
    if (tid < 512) ksum = kP[pidx[tid]];
    ksum += __shfl_xor(ksum,  1);
    ksum += __shfl_xor(ksum,  2);
    ksum += __shfl_xor(ksum,  4);
    ksum += __shfl_xor(ksum,  8);
    ksum += __shfl_xor(ksum, 16);
    ksum += __shfl_xor(ksum, 32);
    if (lane == 0) kpart[wid] = ksum;    // waves 8..15 contribute 0

    // ---- phase 3: chain, depth-2 pipelined. wave w: pairs [32w, 32w+32) ----
    const int base = 32 * wid;
    float* Mseg = Ms + wid * 1152;

    unsigned S0w, S1w, S2w, S3w, S4w, S5w, S6w, S7w;
    {
        const unsigned e0 = ((4*g+0 == jj) ? 0x3F80u : 0u) | ((4*g+1 == jj) ? 0x3F800000u : 0u);
        const unsigned e1 = ((4*g+2 == jj) ? 0x3F80u : 0u) | ((4*g+3 == jj) ? 0x3F800000u : 0u);
        S0w = e0; S1w = e1; S2w = 0u; S3w = 0u;
        S4w = 0u; S5w = 0u; S6w = e0; S7w = e1;
    }

    // prologue: frags for steps 0 and 1 in flight, index for step 2 staged
    const int m0 = pidx[base];
    uint4 F0c = Ptab[m0 * 128 + lane];
    uint4 F1c = Ptab[m0 * 128 + 64 + lane];
    const int m1 = pidx[base + 1];
    uint4 F0n = Ptab[m1 * 128 + lane];
    uint4 F1n = Ptab[m1 * 128 + 64 + lane];
    int   mC  = pidx[base + 2];

#pragma unroll 1
    for (int t = 0; t < 32; ++t) {
        // issue step-(t+2) fragment loads and step-(t+3) index read NOW;
        // both have a full step (~100cy+) before first use.
        const uint4 F0f = Ptab[mC * 128 + lane];
        const uint4 F1f = Ptab[mC * 128 + 64 + lane];
        const int   mN  = pidx[base + t + 3];      // pad zeros beyond 511

        const bf16x8 af0 = as_bf16x8u(F0c);
        const bf16x8 af1 = as_bf16x8u(F1c);
        const bf16x8 sb0 = as_bf16x8u(make_uint4(S0w, S1w, S2w, S3w));
        const bf16x8 sb1 = as_bf16x8u(make_uint4(S4w, S5w, S6w, S7w));
        f32x4 d00 = __builtin_amdgcn_mfma_f32_16x16x32_bf16(af0, sb0, zero, 0, 0, 0);
        f32x4 d01 = __builtin_amdgcn_mfma_f32_16x16x32_bf16(af0, sb1, zero, 0, 0, 0);
        f32x4 d10 = __builtin_amdgcn_mfma_f32_16x16x32_bf16(af1, sb0, zero, 0, 0, 0);
        f32x4 d11 = __builtin_amdgcn_mfma_f32_16x16x32_bf16(af1, sb1, zero, 0, 0, 0);

        if (t == 31) {
            // sigma-free interface: physical f32 D to LDS (m89 layout)
#pragma unroll
            for (int u = 0; u < 4; ++u) {
                Mseg[(4*g + u) * 36 + jj]           = d00[u];
                Mseg[(4*g + u) * 36 + 16 + jj]      = d01[u];
                Mseg[(16 + 4*g + u) * 36 + jj]      = d10[u];
                Mseg[(16 + 4*g + u) * 36 + 16 + jj] = d11[u];
            }
        } else {
            S0w = pkbf16(d00[0], d00[1]);  S1w = pkbf16(d00[2], d00[3]);
            S2w = pkbf16(d10[0], d10[1]);  S3w = pkbf16(d10[2], d10[3]);
            S4w = pkbf16(d01[0], d01[1]);  S5w = pkbf16(d01[2], d01[3]);
            S6w = pkbf16(d11[0], d11[1]);  S7w = pkbf16(d11[2], d11[3]);
        }
        F0c = F0n; F1c = F1n;
        F0n = F0f; F1n = F1f;
        mC = mN;
    }
    __syncthreads();

    // ---- phase 4: tree 16 -> 8 -> 4 -> 2 -> 1, ping-pong slots (r15) -------
    if (wid < 8) {
        const int ec = tree_node_lds(Ms + (2*wid) * 1152, Ms + (2*wid + 1) * 1152,
                                     Ms + (16 + wid) * 1152, lane);
        if (lane == 0) EcA[wid] = ec;
    }
    __syncthreads();
    if (wid < 4) {
        const int ec = tree_node_lds(Ms + (16 + 2*wid) * 1152, Ms + (16 + 2*wid + 1) * 1152,
                                     Ms + wid * 1152, lane);
        if (lane == 0) EcA[8 + wid] = ec;
    }
    __syncthreads();
    if (wid < 2) {
        const int ec = tree_node_lds(Ms + (2*wid) * 1152, Ms + (2*wid + 1) * 1152,
                                     Ms + (16 + wid) * 1152, lane);
        if (lane == 0) EcA[12 + wid] = ec;
    }
    __syncthreads();
    int ecL4 = 0;
    if (wid == 0) {
        ecL4 = tree_node_lds(Ms + 16 * 1152, Ms + 17 * 1152, Ms, lane);
    }

    // ---- phase 5: epilogue: out = L^T P R; S_tot = P^T in slot 0 -----------
    if (wid == 0 && lane < 32) {
        const float* Mt = Ms;
        float v = 0.f;
#pragma unroll 8
        for (int c2 = 0; c2 < 32; ++c2) v = fmaf(Rb[c2], Mt[c2 * 36 + lane], v);
        float pp = v * Lb[lane];
        pp += __shfl_xor(pp,  1);
        pp += __shfl_xor(pp,  2);
        pp += __shfl_xor(pp,  4);
        pp += __shfl_xor(pp,  8);
        pp += __shfl_xor(pp, 16);
        if (lane == 0) {
            int S = ecL4;
#pragma unroll
            for (int w = 0; w < 16; ++w) S += EcA[w] + kpart[w];
            out[b] = 2.0f * ((float)S * 0.6931471805599453f + logf(fabsf(pp)));
        }
    }
}

extern "C" void kernel_launch(void* const* d_in, const int* in_sizes, int n_in,
                              void* d_out, int out_size, void* d_ws, size_t ws_size,
                              hipStream_t stream)
{
    const int*   X    = (const int*)d_in[0];
    const float* core = (const float*)d_in[1];
    const float* Lb   = (const float*)d_in[2];
    const float* Rb   = (const float*)d_in[3];
    float* out = (float*)d_out;

    tt_fused_kernel<<<dim3(256), dim3(1024), 0, stream>>>(X, core, Lb, Rb, out);
}

// Round 19
// 21.498 us; speedup vs baseline: 1.1112x; 1.0130x over previous
//
#include <hip/hip_runtime.h>
#include <math.h>

// Tensor-train log-likelihood, B=256, T=1024, d=4, D=32.
// Round 19 = round 16 math resized for 2 blocks/CU occupancy:
//  - 512 threads (8 waves x 64 chain steps), tree 8->4->2->1 (r14 shape).
//  - LDS 72 KB (< 80): tree ping-pong slots ALIAS Ptab (dead after chain);
//    core staging ALIASES seg slots 4..7 (written only at chain end).
//  - 2 blocks/CU => block A's serial phases (pair build, tree, epilogue)
//    overlap block B's chain. r17/r18 showed the chain itself is dual-pipe
//    throughput-bound; the remaining win is hiding the serial tails.
// All motifs verbatim r16 (PASS absmax 0): pair build + rowsum pow-2 norm,
// sigma-chain MSTEP, tree_node_lds, epilogue fold. No-rescale bound:
// rowsum-normalized pairs => ||prod||_inf <= 2^64, f32/bf16-safe.

#define TT_B 256
#define TT_T 1024

typedef __attribute__((ext_vector_type(8))) short bf16x8;
typedef __attribute__((ext_vector_type(4))) float f32x4;

__device__ __forceinline__ unsigned pkbf16(float lo, float hi)
{
    unsigned r;
    asm volatile("v_cvt_pk_bf16_f32 %0, %1, %2" : "=v"(r) : "v"(lo), "v"(hi));
    return r;
}
__device__ __forceinline__ bf16x8 as_bf16x8(int4 v)
{ union { int4 i; bf16x8 h; } u; u.i = v; return u.h; }
__device__ __forceinline__ bf16x8 as_bf16x8u(uint4 v)
{ union { uint4 i; bf16x8 h; } u; u.i = v; return u.h; }

#define MAXD4(D) fmaxf(fmaxf(fabsf(D[0]), fabsf(D[1])), fmaxf(fabsf(D[2]), fabsf(D[3])))

// tree node (r13-validated, verbatim): node(Ma, Mb) = Mb @ Ma (physical),
// f32 LDS [32][36] both sides, output rescaled by exact pow-2, exp returned.
__device__ __forceinline__ int tree_node_lds(const float* __restrict__ Ma,
                                             const float* __restrict__ Mb,
                                             float* __restrict__ Mdst, int lane)
{
    const int p = lane & 15, q = lane >> 4;
    const float4 a00 = *(const float4*)(Mb + p * 36 + 8 * q);
    const float4 a01 = *(const float4*)(Mb + p * 36 + 8 * q + 4);
    const float4 a10 = *(const float4*)(Mb + (16 + p) * 36 + 8 * q);
    const float4 a11 = *(const float4*)(Mb + (16 + p) * 36 + 8 * q + 4);
    int4 aw0, aw1;
    aw0.x = (int)pkbf16(a00.x, a00.y); aw0.y = (int)pkbf16(a00.z, a00.w);
    aw0.z = (int)pkbf16(a01.x, a01.y); aw0.w = (int)pkbf16(a01.z, a01.w);
    aw1.x = (int)pkbf16(a10.x, a10.y); aw1.y = (int)pkbf16(a10.z, a10.w);
    aw1.z = (int)pkbf16(a11.x, a11.y); aw1.w = (int)pkbf16(a11.z, a11.w);
    int4 bw0, bw1;
    bw0.x = (int)pkbf16(Ma[(8*q+0)*36 + p], Ma[(8*q+1)*36 + p]);
    bw0.y = (int)pkbf16(Ma[(8*q+2)*36 + p], Ma[(8*q+3)*36 + p]);
    bw0.z = (int)pkbf16(Ma[(8*q+4)*36 + p], Ma[(8*q+5)*36 + p]);
    bw0.w = (int)pkbf16(Ma[(8*q+6)*36 + p], Ma[(8*q+7)*36 + p]);
    bw1.x = (int)pkbf16(Ma[(8*q+0)*36 + 16 + p], Ma[(8*q+1)*36 + 16 + p]);
    bw1.y = (int)pkbf16(Ma[(8*q+2)*36 + 16 + p], Ma[(8*q+3)*36 + 16 + p]);
    bw1.z = (int)pkbf16(Ma[(8*q+4)*36 + 16 + p], Ma[(8*q+5)*36 + 16 + p]);
    bw1.w = (int)pkbf16(Ma[(8*q+6)*36 + 16 + p], Ma[(8*q+7)*36 + 16 + p]);

    const bf16x8 af0 = as_bf16x8(aw0), af1 = as_bf16x8(aw1);
    const bf16x8 bf0 = as_bf16x8(bw0), bf1 = as_bf16x8(bw1);
    const f32x4 zero = {0.f, 0.f, 0.f, 0.f};
    f32x4 d00 = __builtin_amdgcn_mfma_f32_16x16x32_bf16(af0, bf0, zero, 0, 0, 0);
    f32x4 d01 = __builtin_amdgcn_mfma_f32_16x16x32_bf16(af0, bf1, zero, 0, 0, 0);
    f32x4 d10 = __builtin_amdgcn_mfma_f32_16x16x32_bf16(af1, bf0, zero, 0, 0, 0);
    f32x4 d11 = __builtin_amdgcn_mfma_f32_16x16x32_bf16(af1, bf1, zero, 0, 0, 0);

    float zm = fmaxf(fmaxf(MAXD4(d00), MAXD4(d01)), fmaxf(MAXD4(d10), MAXD4(d11)));
    zm = fmaxf(zm, __shfl_xor(zm,  1));
    zm = fmaxf(zm, __shfl_xor(zm,  2));
    zm = fmaxf(zm, __shfl_xor(zm,  4));
    zm = fmaxf(zm, __shfl_xor(zm,  8));
    zm = fmaxf(zm, __shfl_xor(zm, 16));
    zm = fmaxf(zm, __shfl_xor(zm, 32));
    const int eb = __float_as_int(zm) & 0x7f800000;
    const float s = __int_as_float(0x7F000000 - eb);
#pragma unroll
    for (int t = 0; t < 4; ++t) {
        Mdst[(4*q + t) * 36 + p]           = d00[t] * s;
        Mdst[(4*q + t) * 36 + 16 + p]      = d01[t] * s;
        Mdst[(16 + 4*q + t) * 36 + p]      = d10[t] * s;
        Mdst[(16 + 4*q + t) * 36 + 16 + p] = d11[t] * s;
    }
    return (eb >> 23) - 127;
}

__global__ __launch_bounds__(512, 4) void tt_fused_kernel(const int* __restrict__ X,
                                                          const float* __restrict__ core,
                                                          const float* __restrict__ Lb,
                                                          const float* __restrict__ Rb,
                                                          float* __restrict__ out)
{
    // seg slots 0..7 (chain-end writes; 4..7 alias core staging pre-chain)
    __shared__ __align__(16) float Ms[8 * 1152];
    // pair table (chain A-operands); tree ping-pong slots alias it post-chain
    __shared__ __align__(16) uint4 Ptab[2048];
    __shared__ int pidx[528];
    __shared__ int kP[16];
    __shared__ int EcA[8];
    __shared__ int kpart[8];

    const int b    = blockIdx.x;
    const int tid  = threadIdx.x;
    const int wid  = tid >> 6;        // 0..7
    const int lane = tid & 63;
    const int p = lane & 15, q = lane >> 4;
    const int g = q, jj = p;

    // ---- phase 0: parse X -> pair indices; core -> seg slots 4..7 ---------
    {
        const int2 xv = ((const int2*)(X + (size_t)b * TT_T))[tid];
        pidx[tid] = xv.x * 4 + xv.y;
    }
    if (tid < 16) { pidx[512 + tid] = 0; }          // chain lookahead pad
    if (tid < 8)  { EcA[tid] = 0; }
    if (wid >= 4) {                                  // cores 0..3 -> slots 4..7
        const int mi = wid - 4;
        const int r = lane >> 1, hh = (lane & 1) * 16;
        const float4* s4 = (const float4*)(core + mi * 1024 + r * 32 + hh);
        float4 v0 = s4[0], v1 = s4[1], v2 = s4[2], v3 = s4[3];
        float4* d4 = (float4*)(Ms + (4 + mi) * 1152 + r * 36 + hh);
        d4[0] = v0; d4[1] = v1; d4[2] = v2; d4[3] = v3;
    }
    __syncthreads();

    const f32x4 zero = {0.f, 0.f, 0.f, 0.f};

    // ---- phase 1: pair table. wave w builds pairs 2w, 2w+1 ------------------
#pragma unroll
    for (int pp2 = 0; pp2 < 2; ++pp2) {
        const int m = 2 * wid + pp2;                 // P_m = M_{m>>2} @ M_{m&3}
        const float* Pa = Ms + (4 + (m & 3)) * 1152;   // B-frag source
        const float* Pb = Ms + (4 + (m >> 2)) * 1152;  // A-frag source
        const float4 a00 = *(const float4*)(Pb + p * 36 + 8 * q);
        const float4 a01 = *(const float4*)(Pb + p * 36 + 8 * q + 4);
        const float4 a10 = *(const float4*)(Pb + (16 + p) * 36 + 8 * q);
        const float4 a11 = *(const float4*)(Pb + (16 + p) * 36 + 8 * q + 4);
        int4 aw0, aw1;
        aw0.x = (int)pkbf16(a00.x, a00.y); aw0.y = (int)pkbf16(a00.z, a00.w);
        aw0.z = (int)pkbf16(a01.x, a01.y); aw0.w = (int)pkbf16(a01.z, a01.w);
        aw1.x = (int)pkbf16(a10.x, a10.y); aw1.y = (int)pkbf16(a10.z, a10.w);
        aw1.z = (int)pkbf16(a11.x, a11.y); aw1.w = (int)pkbf16(a11.z, a11.w);
        int4 bw0, bw1;
        bw0.x = (int)pkbf16(Pa[(8*q+0)*36 + p], Pa[(8*q+1)*36 + p]);
        bw0.y = (int)pkbf16(Pa[(8*q+2)*36 + p], Pa[(8*q+3)*36 + p]);
        bw0.z = (int)pkbf16(Pa[(8*q+4)*36 + p], Pa[(8*q+5)*36 + p]);
        bw0.w = (int)pkbf16(Pa[(8*q+6)*36 + p], Pa[(8*q+7)*36 + p]);
        bw1.x = (int)pkbf16(Pa[(8*q+0)*36 + 16 + p], Pa[(8*q+1)*36 + 16 + p]);
        bw1.y = (int)pkbf16(Pa[(8*q+2)*36 + 16 + p], Pa[(8*q+3)*36 + 16 + p]);
        bw1.z = (int)pkbf16(Pa[(8*q+4)*36 + 16 + p], Pa[(8*q+5)*36 + 16 + p]);
        bw1.w = (int)pkbf16(Pa[(8*q+6)*36 + 16 + p], Pa[(8*q+7)*36 + 16 + p]);
        const bf16x8 af0 = as_bf16x8(aw0), af1 = as_bf16x8(aw1);
        const bf16x8 bf0 = as_bf16x8(bw0), bf1 = as_bf16x8(bw1);
        f32x4 d00 = __builtin_amdgcn_mfma_f32_16x16x32_bf16(af0, bf0, zero, 0, 0, 0);
        f32x4 d01 = __builtin_amdgcn_mfma_f32_16x16x32_bf16(af0, bf1, zero, 0, 0, 0);
        f32x4 d10 = __builtin_amdgcn_mfma_f32_16x16x32_bf16(af1, bf0, zero, 0, 0, 0);
        f32x4 d11 = __builtin_amdgcn_mfma_f32_16x16x32_bf16(af1, bf1, zero, 0, 0, 0);

        // rowsum-normalize (exact pow-2) -- r16 verbatim
        float rs[4], ru[4];
#pragma unroll
        for (int t = 0; t < 4; ++t) {
            rs[t] = fabsf(d00[t]) + fabsf(d01[t]);
            ru[t] = fabsf(d10[t]) + fabsf(d11[t]);
        }
#pragma unroll
        for (int sh = 1; sh <= 8; sh <<= 1) {
#pragma unroll
            for (int t = 0; t < 4; ++t) {
                rs[t] += __shfl_xor(rs[t], sh);
                ru[t] += __shfl_xor(ru[t], sh);
            }
        }
        float mx = fmaxf(fmaxf(fmaxf(rs[0], rs[1]), fmaxf(rs[2], rs[3])),
                         fmaxf(fmaxf(ru[0], ru[1]), fmaxf(ru[2], ru[3])));
        mx = fmaxf(mx, __shfl_xor(mx, 16));
        mx = fmaxf(mx, __shfl_xor(mx, 32));
        const int eb = __float_as_int(mx) & 0x7f800000;
        const float s = __int_as_float(0x7F000000 - eb);
        if (lane == 0) kP[m] = (eb >> 23) - 127;

        uint4 H0, H1;
        H0.x = pkbf16(d00[0]*s, d00[1]*s);  H0.y = pkbf16(d00[2]*s, d00[3]*s);
        H0.z = pkbf16(d10[0]*s, d10[1]*s);  H0.w = pkbf16(d10[2]*s, d10[3]*s);
        H1.x = pkbf16(d01[0]*s, d01[1]*s);  H1.y = pkbf16(d01[2]*s, d01[3]*s);
        H1.z = pkbf16(d11[0]*s, d11[1]*s);  H1.w = pkbf16(d11[2]*s, d11[3]*s);
        Ptab[m * 128 + lane]      = H0;
        Ptab[m * 128 + 64 + lane] = H1;
    }
    __syncthreads();

    // ---- phase 2: per-sequence exponent sum over 512 pair-applications ----
    int ksum = kP[pidx[tid]];
    ksum += __shfl_xor(ksum,  1);
    ksum += __shfl_xor(ksum,  2);
    ksum += __shfl_xor(ksum,  4);
    ksum += __shfl_xor(ksum,  8);
    ksum += __shfl_xor(ksum, 16);
    ksum += __shfl_xor(ksum, 32);
    if (lane == 0) kpart[wid] = ksum;

    // ---- phase 3: chain (r16 loop). wave w: pairs [64w, 64w+64) ------------
    const int base = 64 * wid;
    float* Mseg = Ms + wid * 1152;

    unsigned S0w, S1w, S2w, S3w, S4w, S5w, S6w, S7w;
    {
        const unsigned e0 = ((4*g+0 == jj) ? 0x3F80u : 0u) | ((4*g+1 == jj) ? 0x3F800000u : 0u);
        const unsigned e1 = ((4*g+2 == jj) ? 0x3F80u : 0u) | ((4*g+3 == jj) ? 0x3F800000u : 0u);
        S0w = e0; S1w = e1; S2w = 0u; S3w = 0u;
        S4w = 0u; S5w = 0u; S6w = e0; S7w = e1;
    }

    const int m0 = pidx[base];
    uint4 F0c = Ptab[m0 * 128 + lane];
    uint4 F1c = Ptab[m0 * 128 + 64 + lane];

#pragma unroll 1
    for (int t = 0; t < 64; ++t) {
        const int mn = pidx[base + t + 1];           // t=63 reads pad (0)
        const uint4 F0n = Ptab[mn * 128 + lane];
        const uint4 F1n = Ptab[mn * 128 + 64 + lane];

        const bf16x8 af0 = as_bf16x8u(F0c);
        const bf16x8 af1 = as_bf16x8u(F1c);
        const bf16x8 sb0 = as_bf16x8u(make_uint4(S0w, S1w, S2w, S3w));
        const bf16x8 sb1 = as_bf16x8u(make_uint4(S4w, S5w, S6w, S7w));
        f32x4 d00 = __builtin_amdgcn_mfma_f32_16x16x32_bf16(af0, sb0, zero, 0, 0, 0);
        f32x4 d01 = __builtin_amdgcn_mfma_f32_16x16x32_bf16(af0, sb1, zero, 0, 0, 0);
        f32x4 d10 = __builtin_amdgcn_mfma_f32_16x16x32_bf16(af1, sb0, zero, 0, 0, 0);
        f32x4 d11 = __builtin_amdgcn_mfma_f32_16x16x32_bf16(af1, sb1, zero, 0, 0, 0);

        if (t == 63) {
            // sigma-free interface: physical f32 D to LDS (m89 layout)
#pragma unroll
            for (int u = 0; u < 4; ++u) {
                Mseg[(4*g + u) * 36 + jj]           = d00[u];
                Mseg[(4*g + u) * 36 + 16 + jj]      = d01[u];
                Mseg[(16 + 4*g + u) * 36 + jj]      = d10[u];
                Mseg[(16 + 4*g + u) * 36 + 16 + jj] = d11[u];
            }
        } else {
            S0w = pkbf16(d00[0], d00[1]);  S1w = pkbf16(d00[2], d00[3]);
            S2w = pkbf16(d10[0], d10[1]);  S3w = pkbf16(d10[2], d10[3]);
            S4w = pkbf16(d01[0], d01[1]);  S5w = pkbf16(d01[2], d01[3]);
            S6w = pkbf16(d11[0], d11[1]);  S7w = pkbf16(d11[2], d11[3]);
        }
        F0c = F0n; F1c = F1n;
    }
    __syncthreads();

    // ---- phase 4: tree 8 -> 4 -> 2 -> 1; temp slots alias Ptab --------------
    float* Mt = (float*)Ptab;     // 8192 floats = 7 slots of 1152 (7 needed)
    if (wid < 4) {
        const int ec = tree_node_lds(Ms + (2*wid) * 1152, Ms + (2*wid + 1) * 1152,
                                     Mt + wid * 1152, lane);
        if (lane == 0) EcA[wid] = ec;
    }
    __syncthreads();
    if (wid < 2) {
        const int ec = tree_node_lds(Mt + (2*wid) * 1152, Mt + (2*wid + 1) * 1152,
                                     Mt + (4 + wid) * 1152, lane);
        if (lane == 0) EcA[4 + wid] = ec;
    }
    __syncthreads();
    int ecL3 = 0;
    if (wid == 0) {
        ecL3 = tree_node_lds(Mt + 4 * 1152, Mt + 5 * 1152, Mt + 6 * 1152, lane);
    }

    // ---- phase 5: epilogue: out = L^T P R; S_tot = P^T in Mt slot 6 --------
    if (wid == 0 && lane < 32) {
        const float* Mf = Mt + 6 * 1152;
        float v = 0.f;
#pragma unroll 8
        for (int c2 = 0; c2 < 32; ++c2) v = fmaf(Rb[c2], Mf[c2 * 36 + lane], v);
        float pp = v * Lb[lane];
        pp += __shfl_xor(pp,  1);
        pp += __shfl_xor(pp,  2);
        pp += __shfl_xor(pp,  4);
        pp += __shfl_xor(pp,  8);
        pp += __shfl_xor(pp, 16);
        if (lane == 0) {
            int S = ecL3;
#pragma unroll
            for (int w = 0; w < 6; ++w) S += EcA[w];
#pragma unroll
            for (int w = 0; w < 8; ++w) S += kpart[w];
            out[b] = 2.0f * ((float)S * 0.6931471805599453f + logf(fabsf(pp)));
        }
    }
}

extern "C" void kernel_launch(void* const* d_in, const int* in_sizes, int n_in,
                              void* d_out, int out_size, void* d_ws, size_t ws_size,
                              hipStream_t stream)
{
    const int*   X    = (const int*)d_in[0];
    const float* core = (const float*)d_in[1];
    const float* Lb   = (const float*)d_in[2];
    const float* Rb   = (const float*)d_in[3];
    float* out = (float*)d_out;

    tt_fused_kernel<<<dim3(256), dim3(512), 0, stream>>>(X, core, Lb, Rb, out);
}

// Round 20
// 20.926 us; speedup vs baseline: 1.1416x; 1.0273x over previous
//
#include <hip/hip_runtime.h>
#include <math.h>

// Tensor-train log-likelihood, B=256, T=1024, d=4, D=32.
// FINAL (= round 16, best measured: 21.02us, PASS absmax 0.0).
// Single fused kernel. Per-block LDS pair table (d^2=16 products Ma@Mb,
// built by 16 waves with 4 MFMAs each, rowsum-normalized exact pow-2,
// stored directly as sigma-fragments: the D->S pack formula == the table
// A-frag layout under sigma(g,s)=4g+(s&3)+16*(s>>2)). Chain: 16 waves x
// 32 pair-steps, operands from LDS. Tree (16->8->4->2->1 ping-pong) +
// epilogue fold. Rowsum norm => ||S||_1 <= 2^32 over 32 steps: no
// in-chain rescale. All exponents (16 tree nodes + per-pair k) exact
// pow-2, summed at the end.
// Floor notes (r17-r19 nulls): global-table split +2.9us, depth-2 LDS
// pipeline +0.75us, 2-blocks/CU +0.5us -- kernel is multi-pipe balanced;
// remaining time ~6us harness/launch + overlapped MFMA/LDS/VALU phases.

#define TT_B 256
#define TT_T 1024

typedef __attribute__((ext_vector_type(8))) short bf16x8;
typedef __attribute__((ext_vector_type(4))) float f32x4;

__device__ __forceinline__ unsigned pkbf16(float lo, float hi)
{
    unsigned r;
    asm volatile("v_cvt_pk_bf16_f32 %0, %1, %2" : "=v"(r) : "v"(lo), "v"(hi));
    return r;
}
__device__ __forceinline__ bf16x8 as_bf16x8(int4 v)
{ union { int4 i; bf16x8 h; } u; u.i = v; return u.h; }
__device__ __forceinline__ bf16x8 as_bf16x8u(uint4 v)
{ union { uint4 i; bf16x8 h; } u; u.i = v; return u.h; }

#define MAXD4(D) fmaxf(fmaxf(fabsf(D[0]), fabsf(D[1])), fmaxf(fabsf(D[2]), fabsf(D[3])))

// tree node (r13-validated): node(Ma, Mb) = Mb @ Ma (physical), f32 LDS
// [32][36] both sides, output rescaled by exact pow-2, exponent returned.
__device__ __forceinline__ int tree_node_lds(const float* __restrict__ Ma,
                                             const float* __restrict__ Mb,
                                             float* __restrict__ Mdst, int lane)
{
    const int p = lane & 15, q = lane >> 4;
    const float4 a00 = *(const float4*)(Mb + p * 36 + 8 * q);
    const float4 a01 = *(const float4*)(Mb + p * 36 + 8 * q + 4);
    const float4 a10 = *(const float4*)(Mb + (16 + p) * 36 + 8 * q);
    const float4 a11 = *(const float4*)(Mb + (16 + p) * 36 + 8 * q + 4);
    int4 aw0, aw1;
    aw0.x = (int)pkbf16(a00.x, a00.y); aw0.y = (int)pkbf16(a00.z, a00.w);
    aw0.z = (int)pkbf16(a01.x, a01.y); aw0.w = (int)pkbf16(a01.z, a01.w);
    aw1.x = (int)pkbf16(a10.x, a10.y); aw1.y = (int)pkbf16(a10.z, a10.w);
    aw1.z = (int)pkbf16(a11.x, a11.y); aw1.w = (int)pkbf16(a11.z, a11.w);
    int4 bw0, bw1;
    bw0.x = (int)pkbf16(Ma[(8*q+0)*36 + p], Ma[(8*q+1)*36 + p]);
    bw0.y = (int)pkbf16(Ma[(8*q+2)*36 + p], Ma[(8*q+3)*36 + p]);
    bw0.z = (int)pkbf16(Ma[(8*q+4)*36 + p], Ma[(8*q+5)*36 + p]);
    bw0.w = (int)pkbf16(Ma[(8*q+6)*36 + p], Ma[(8*q+7)*36 + p]);
    bw1.x = (int)pkbf16(Ma[(8*q+0)*36 + 16 + p], Ma[(8*q+1)*36 + 16 + p]);
    bw1.y = (int)pkbf16(Ma[(8*q+2)*36 + 16 + p], Ma[(8*q+3)*36 + 16 + p]);
    bw1.z = (int)pkbf16(Ma[(8*q+4)*36 + 16 + p], Ma[(8*q+5)*36 + 16 + p]);
    bw1.w = (int)pkbf16(Ma[(8*q+6)*36 + 16 + p], Ma[(8*q+7)*36 + 16 + p]);

    const bf16x8 af0 = as_bf16x8(aw0), af1 = as_bf16x8(aw1);
    const bf16x8 bf0 = as_bf16x8(bw0), bf1 = as_bf16x8(bw1);
    const f32x4 zero = {0.f, 0.f, 0.f, 0.f};
    f32x4 d00 = __builtin_amdgcn_mfma_f32_16x16x32_bf16(af0, bf0, zero, 0, 0, 0);
    f32x4 d01 = __builtin_amdgcn_mfma_f32_16x16x32_bf16(af0, bf1, zero, 0, 0, 0);
    f32x4 d10 = __builtin_amdgcn_mfma_f32_16x16x32_bf16(af1, bf0, zero, 0, 0, 0);
    f32x4 d11 = __builtin_amdgcn_mfma_f32_16x16x32_bf16(af1, bf1, zero, 0, 0, 0);

    float zm = fmaxf(fmaxf(MAXD4(d00), MAXD4(d01)), fmaxf(MAXD4(d10), MAXD4(d11)));
    zm = fmaxf(zm, __shfl_xor(zm,  1));
    zm = fmaxf(zm, __shfl_xor(zm,  2));
    zm = fmaxf(zm, __shfl_xor(zm,  4));
    zm = fmaxf(zm, __shfl_xor(zm,  8));
    zm = fmaxf(zm, __shfl_xor(zm, 16));
    zm = fmaxf(zm, __shfl_xor(zm, 32));
    const int eb = __float_as_int(zm) & 0x7f800000;
    const float s = __int_as_float(0x7F000000 - eb);
#pragma unroll
    for (int t = 0; t < 4; ++t) {
        Mdst[(4*q + t) * 36 + p]           = d00[t] * s;
        Mdst[(4*q + t) * 36 + 16 + p]      = d01[t] * s;
        Mdst[(16 + 4*q + t) * 36 + p]      = d10[t] * s;
        Mdst[(16 + 4*q + t) * 36 + 16 + p] = d11[t] * s;
    }
    return (eb >> 23) - 127;
}

__global__ __launch_bounds__(1024, 1) void tt_fused_kernel(const int* __restrict__ X,
                                                           const float* __restrict__ core,
                                                           const float* __restrict__ Lb,
                                                           const float* __restrict__ Rb,
                                                           float* __restrict__ out)
{
    __shared__ __align__(16) float Ms[24 * 1152];   // tree slots; 16..19 alias core
    __shared__ __align__(16) uint4 Ptab[2048];      // 16 pairs x 2 halves x 64 lanes
    __shared__ int pidx[544];
    __shared__ int kP[16];
    __shared__ int EcA[16];
    __shared__ int kpart[16];

    const int b    = blockIdx.x;
    const int tid  = threadIdx.x;
    const int wid  = tid >> 6;        // 0..15
    const int lane = tid & 63;
    const int p = lane & 15, q = lane >> 4;
    const int g = q, jj = p;

    // ---- phase 0: parse X -> pair indices; load core -> slots 16..19 ------
    if (tid < 512) {
        const int2 xv = ((const int2*)(X + (size_t)b * TT_T))[tid];
        pidx[tid] = xv.x * 4 + xv.y;
    } else if (tid < 544) {
        pidx[tid] = 0;                // pad for chain lookahead
    }
    if (tid < 16) EcA[tid] = 0;
    if (wid >= 8 && wid < 12) {
        const int mi = wid - 8;
        const int r = lane >> 1, hh = (lane & 1) * 16;
        const float4* s4 = (const float4*)(core + mi * 1024 + r * 32 + hh);
        float4 v0 = s4[0], v1 = s4[1], v2 = s4[2], v3 = s4[3];
        float4* d4 = (float4*)(Ms + (16 + mi) * 1152 + r * 36 + hh);
        d4[0] = v0; d4[1] = v1; d4[2] = v2; d4[3] = v3;
    }
    __syncthreads();

    const f32x4 zero = {0.f, 0.f, 0.f, 0.f};

    // ---- phase 1: pair table. wave w: P = M_{w>>2} @ M_{w&3} ----------------
    {
        const float* Pa = Ms + (16 + (wid & 3)) * 1152;   // B-frag source (scalar cols)
        const float* Pb = Ms + (16 + (wid >> 2)) * 1152;  // A-frag source (float4 rows)
        const float4 a00 = *(const float4*)(Pb + p * 36 + 8 * q);
        const float4 a01 = *(const float4*)(Pb + p * 36 + 8 * q + 4);
        const float4 a10 = *(const float4*)(Pb + (16 + p) * 36 + 8 * q);
        const float4 a11 = *(const float4*)(Pb + (16 + p) * 36 + 8 * q + 4);
        int4 aw0, aw1;
        aw0.x = (int)pkbf16(a00.x, a00.y); aw0.y = (int)pkbf16(a00.z, a00.w);
        aw0.z = (int)pkbf16(a01.x, a01.y); aw0.w = (int)pkbf16(a01.z, a01.w);
        aw1.x = (int)pkbf16(a10.x, a10.y); aw1.y = (int)pkbf16(a10.z, a10.w);
        aw1.z = (int)pkbf16(a11.x, a11.y); aw1.w = (int)pkbf16(a11.z, a11.w);
        int4 bw0, bw1;
        bw0.x = (int)pkbf16(Pa[(8*q+0)*36 + p], Pa[(8*q+1)*36 + p]);
        bw0.y = (int)pkbf16(Pa[(8*q+2)*36 + p], Pa[(8*q+3)*36 + p]);
        bw0.z = (int)pkbf16(Pa[(8*q+4)*36 + p], Pa[(8*q+5)*36 + p]);
        bw0.w = (int)pkbf16(Pa[(8*q+6)*36 + p], Pa[(8*q+7)*36 + p]);
        bw1.x = (int)pkbf16(Pa[(8*q+0)*36 + 16 + p], Pa[(8*q+1)*36 + 16 + p]);
        bw1.y = (int)pkbf16(Pa[(8*q+2)*36 + 16 + p], Pa[(8*q+3)*36 + 16 + p]);
        bw1.z = (int)pkbf16(Pa[(8*q+4)*36 + 16 + p], Pa[(8*q+5)*36 + 16 + p]);
        bw1.w = (int)pkbf16(Pa[(8*q+6)*36 + 16 + p], Pa[(8*q+7)*36 + 16 + p]);
        const bf16x8 af0 = as_bf16x8(aw0), af1 = as_bf16x8(aw1);
        const bf16x8 bf0 = as_bf16x8(bw0), bf1 = as_bf16x8(bw1);
        f32x4 d00 = __builtin_amdgcn_mfma_f32_16x16x32_bf16(af0, bf0, zero, 0, 0, 0);
        f32x4 d01 = __builtin_amdgcn_mfma_f32_16x16x32_bf16(af0, bf1, zero, 0, 0, 0);
        f32x4 d10 = __builtin_amdgcn_mfma_f32_16x16x32_bf16(af1, bf0, zero, 0, 0, 0);
        f32x4 d11 = __builtin_amdgcn_mfma_f32_16x16x32_bf16(af1, bf1, zero, 0, 0, 0);

        // rowsum-normalize (exact pow-2): lane(q,p) holds rows {4q+t},
        // {16+4q+t}, cols p and 16+p.
        float rs[4], ru[4];
#pragma unroll
        for (int t = 0; t < 4; ++t) {
            rs[t] = fabsf(d00[t]) + fabsf(d01[t]);
            ru[t] = fabsf(d10[t]) + fabsf(d11[t]);
        }
#pragma unroll
        for (int sh = 1; sh <= 8; sh <<= 1) {
#pragma unroll
            for (int t = 0; t < 4; ++t) {
                rs[t] += __shfl_xor(rs[t], sh);
                ru[t] += __shfl_xor(ru[t], sh);
            }
        }
        float mx = fmaxf(fmaxf(fmaxf(rs[0], rs[1]), fmaxf(rs[2], rs[3])),
                         fmaxf(fmaxf(ru[0], ru[1]), fmaxf(ru[2], ru[3])));
        mx = fmaxf(mx, __shfl_xor(mx, 16));
        mx = fmaxf(mx, __shfl_xor(mx, 32));
        const int eb = __float_as_int(mx) & 0x7f800000;
        const float s = __int_as_float(0x7F000000 - eb);
        if (lane == 0) kP[wid] = (eb >> 23) - 127;

        // pack (D->S form == table A-frag form under sigma) into pair table
        uint4 H0, H1;
        H0.x = pkbf16(d00[0]*s, d00[1]*s);  H0.y = pkbf16(d00[2]*s, d00[3]*s);
        H0.z = pkbf16(d10[0]*s, d10[1]*s);  H0.w = pkbf16(d10[2]*s, d10[3]*s);
        H1.x = pkbf16(d01[0]*s, d01[1]*s);  H1.y = pkbf16(d01[2]*s, d01[3]*s);
        H1.z = pkbf16(d11[0]*s, d11[1]*s);  H1.w = pkbf16(d11[2]*s, d11[3]*s);
        Ptab[wid * 128 + lane]      = H0;
        Ptab[wid * 128 + 64 + lane] = H1;
    }
    __syncthreads();

    // ---- phase 2: per-sequence exponent sum over 512 pair-applications ----
    int ksum = 0;
    if (tid < 512) ksum = kP[pidx[tid]];
    ksum += __shfl_xor(ksum,  1);
    ksum += __shfl_xor(ksum,  2);
    ksum += __shfl_xor(ksum,  4);
    ksum += __shfl_xor(ksum,  8);
    ksum += __shfl_xor(ksum, 16);
    ksum += __shfl_xor(ksum, 32);
    if (lane == 0) kpart[wid] = ksum;    // waves 8..15 contribute 0

    // ---- phase 3: chain. wave w: pairs [32w, 32w+32), S = (prod P)^T -------
    const int base = 32 * wid;
    float* Mseg = Ms + wid * 1152;

    unsigned S0w, S1w, S2w, S3w, S4w, S5w, S6w, S7w;
    {
        const unsigned e0 = ((4*g+0 == jj) ? 0x3F80u : 0u) | ((4*g+1 == jj) ? 0x3F800000u : 0u);
        const unsigned e1 = ((4*g+2 == jj) ? 0x3F80u : 0u) | ((4*g+3 == jj) ? 0x3F800000u : 0u);
        S0w = e0; S1w = e1; S2w = 0u; S3w = 0u;
        S4w = 0u; S5w = 0u; S6w = e0; S7w = e1;
    }

    const int m0 = pidx[base];
    uint4 F0c = Ptab[m0 * 128 + lane];
    uint4 F1c = Ptab[m0 * 128 + 64 + lane];

#pragma unroll 1
    for (int t = 0; t < 32; ++t) {
        const int mn = pidx[base + t + 1];           // t=31 reads pad (0)
        const uint4 F0n = Ptab[mn * 128 + lane];
        const uint4 F1n = Ptab[mn * 128 + 64 + lane];

        const bf16x8 af0 = as_bf16x8u(F0c);
        const bf16x8 af1 = as_bf16x8u(F1c);
        const bf16x8 sb0 = as_bf16x8u(make_uint4(S0w, S1w, S2w, S3w));
        const bf16x8 sb1 = as_bf16x8u(make_uint4(S4w, S5w, S6w, S7w));
        f32x4 d00 = __builtin_amdgcn_mfma_f32_16x16x32_bf16(af0, sb0, zero, 0, 0, 0);
        f32x4 d01 = __builtin_amdgcn_mfma_f32_16x16x32_bf16(af0, sb1, zero, 0, 0, 0);
        f32x4 d10 = __builtin_amdgcn_mfma_f32_16x16x32_bf16(af1, sb0, zero, 0, 0, 0);
        f32x4 d11 = __builtin_amdgcn_mfma_f32_16x16x32_bf16(af1, sb1, zero, 0, 0, 0);

        if (t == 31) {
            // sigma-free interface: physical f32 D to LDS (m89 layout)
#pragma unroll
            for (int u = 0; u < 4; ++u) {
                Mseg[(4*g + u) * 36 + jj]           = d00[u];
                Mseg[(4*g + u) * 36 + 16 + jj]      = d01[u];
                Mseg[(16 + 4*g + u) * 36 + jj]      = d10[u];
                Mseg[(16 + 4*g + u) * 36 + 16 + jj] = d11[u];
            }
        } else {
            S0w = pkbf16(d00[0], d00[1]);  S1w = pkbf16(d00[2], d00[3]);
            S2w = pkbf16(d10[0], d10[1]);  S3w = pkbf16(d10[2], d10[3]);
            S4w = pkbf16(d01[0], d01[1]);  S5w = pkbf16(d01[2], d01[3]);
            S6w = pkbf16(d11[0], d11[1]);  S7w = pkbf16(d11[2], d11[3]);
        }
        F0c = F0n; F1c = F1n;
    }
    __syncthreads();

    // ---- phase 4: tree 16 -> 8 -> 4 -> 2 -> 1, ping-pong slots -------------
    if (wid < 8) {
        const int ec = tree_node_lds(Ms + (2*wid) * 1152, Ms + (2*wid + 1) * 1152,
                                     Ms + (16 + wid) * 1152, lane);
        if (lane == 0) EcA[wid] = ec;
    }
    __syncthreads();
    if (wid < 4) {
        const int ec = tree_node_lds(Ms + (16 + 2*wid) * 1152, Ms + (16 + 2*wid + 1) * 1152,
                                     Ms + wid * 1152, lane);
        if (lane == 0) EcA[8 + wid] = ec;
    }
    __syncthreads();
    if (wid < 2) {
        const int ec = tree_node_lds(Ms + (2*wid) * 1152, Ms + (2*wid + 1) * 1152,
                                     Ms + (16 + wid) * 1152, lane);
        if (lane == 0) EcA[12 + wid] = ec;
    }
    __syncthreads();
    int ecL4 = 0;
    if (wid == 0) {
        ecL4 = tree_node_lds(Ms + 16 * 1152, Ms + 17 * 1152, Ms, lane);
    }

    // ---- phase 5: epilogue: out = L^T P R; S_tot = P^T in slot 0 -----------
    if (wid == 0 && lane < 32) {
        const float* Mt = Ms;
        float v = 0.f;
#pragma unroll 8
        for (int c2 = 0; c2 < 32; ++c2) v = fmaf(Rb[c2], Mt[c2 * 36 + lane], v);
        float pp = v * Lb[lane];
        pp += __shfl_xor(pp,  1);
        pp += __shfl_xor(pp,  2);
        pp += __shfl_xor(pp,  4);
        pp += __shfl_xor(pp,  8);
        pp += __shfl_xor(pp, 16);
        if (lane == 0) {
            int S = ecL4;
#pragma unroll
            for (int w = 0; w < 16; ++w) S += EcA[w] + kpart[w];
            out[b] = 2.0f * ((float)S * 0.6931471805599453f + logf(fabsf(pp)));
        }
    }
}

extern "C" void kernel_launch(void* const* d_in, const int* in_sizes, int n_in,
                              void* d_out, int out_size, void* d_ws, size_t ws_size,
                              hipStream_t stream)
{
    const int*   X    = (const int*)d_in[0];
    const float* core = (const float*)d_in[1];
    const float* Lb   = (const float*)d_in[2];
    const float* Rb   = (const float*)d_in[3];
    float* out = (float*)d_out;

    tt_fused_kernel<<<dim3(256), dim3(1024), 0, stream>>>(X, core, Lb, Rb, out);
}